// Round 6
// baseline (138.532 us; speedup 1.0000x reference)
//
#include <hip/hip_runtime.h>

#define BB 64
#define NN 512
#define FD 64

typedef short bf16x8 __attribute__((ext_vector_type(8)));
typedef float f32x4 __attribute__((ext_vector_type(4)));

__device__ __forceinline__ unsigned short f2bf(float f){
    unsigned u = __builtin_bit_cast(unsigned, f);
    u += 0x7fffu + ((u >> 16) & 1u);           // RNE
    return (unsigned short)(u >> 16);
}
__device__ __forceinline__ float bf2f(unsigned short h){
    unsigned u = ((unsigned)h) << 16;
    return __builtin_bit_cast(float, u);
}
__device__ __forceinline__ float fast_tanh(float x){
    float e = __expf(2.0f * x);                 // inf -> 1, 0 -> -1: saturates correctly
    return 1.0f - 2.0f * __builtin_amdgcn_rcpf(e + 1.0f);
}

// XW = X @ W via MFMA (W transposed in-block);
// emits XWh[b][n][f] (natural) and XWt[b][f][n] (transposed), bf16
__global__ __launch_bounds__(256) void k_xw(const float* __restrict__ X,
                                            const float* __restrict__ W,
                                            unsigned short* __restrict__ XWh,
                                            unsigned short* __restrict__ XWt){
    __shared__ unsigned short Xl[64][72];
    __shared__ unsigned short Wtl[64][72];
    __shared__ unsigned short Cl[64][72];    // C natural [n][f]
    __shared__ unsigned short ClT[64][72];   // C transposed [f][n]
    int t = threadIdx.x;
    int row0 = blockIdx.x * 64;
    int r = t >> 2, c0 = (t & 3) * 16;
    {   // W rows r (c-index) -> scatter transpose to Wtl[d][c]
        const float4* wsrc = (const float4*)&W[r*64 + c0];
        #pragma unroll
        for (int q = 0; q < 4; q++){
            float4 v = wsrc[q];
            Wtl[c0 + q*4 + 0][r] = f2bf(v.x);
            Wtl[c0 + q*4 + 1][r] = f2bf(v.y);
            Wtl[c0 + q*4 + 2][r] = f2bf(v.z);
            Wtl[c0 + q*4 + 3][r] = f2bf(v.w);
        }
        const float4* src = (const float4*)&X[(row0 + r)*FD + c0];
        #pragma unroll
        for (int q = 0; q < 4; q++){
            float4 v = src[q];
            ushort4 h; h.x=f2bf(v.x); h.y=f2bf(v.y); h.z=f2bf(v.z); h.w=f2bf(v.w);
            *(ushort4*)&Xl[r][c0 + q*4] = h;
        }
    }
    __syncthreads();
    int lane = t & 63, w = t >> 6, l15 = lane & 15, quad = lane >> 4;
    f32x4 acc[4] = {{0,0,0,0},{0,0,0,0},{0,0,0,0},{0,0,0,0}};
    #pragma unroll
    for (int ks = 0; ks < 2; ks++){
        bf16x8 af = *(const bf16x8*)&Xl[w*16 + l15][ks*32 + quad*8];
        #pragma unroll
        for (int nt = 0; nt < 4; nt++){
            bf16x8 bfr = *(const bf16x8*)&Wtl[nt*16 + l15][ks*32 + quad*8];
            acc[nt] = __builtin_amdgcn_mfma_f32_16x16x32_bf16(af, bfr, acc[nt], 0, 0, 0);
        }
    }
    #pragma unroll
    for (int nt = 0; nt < 4; nt++)
        #pragma unroll
        for (int rg = 0; rg < 4; rg++){
            unsigned short hb = f2bf(acc[nt][rg]);
            Cl [w*16 + quad*4 + rg][nt*16 + l15] = hb;
            ClT[nt*16 + l15][w*16 + quad*4 + rg] = hb;
        }
    __syncthreads();
    int b = blockIdx.x >> 3, n0 = (blockIdx.x & 7) * 64;
    {
        uint4 v0 = *(const uint4*)&Cl[r][c0];
        uint4 v1 = *(const uint4*)&Cl[r][c0 + 8];
        *(uint4*)&XWh[(row0 + r)*FD + c0]     = v0;
        *(uint4*)&XWh[(row0 + r)*FD + c0 + 8] = v1;
    }
    {
        uint4 v0 = *(const uint4*)&ClT[r][c0];
        uint4 v1 = *(const uint4*)&ClT[r][c0 + 8];
        *(uint4*)&XWt[(b*64 + r)*NN + n0 + c0]     = v0;
        *(uint4*)&XWt[(b*64 + r)*NN + n0 + c0 + 8] = v1;
    }
}

// Fused per 64-row i-tile: M = (A_ @ XW) * diag(colsum) in LDS, then
// H = tanh(M @ XW^T + rowsum*bias_a) @ XW + bias_W  (flash over 8 j-chunks)
// 512 thr / 8 waves: wave w -> rows (w&3)*16, cols (w>>2)*32 (2 MFMA col-tiles)
// buf slots: phase A: [c&1]=A chunk dbuf, [2+(c&1)]=XWt dbuf
//            phase B: [0]=XWh (single), [1]/[3]=XWt dbuf, [2]=M then P
__global__ __launch_bounds__(512, 6) void k_fused(const float* __restrict__ A,
                                                  const unsigned short* __restrict__ XWh,
                                                  const unsigned short* __restrict__ XWt,
                                                  const float* __restrict__ a,
                                                  const int* __restrict__ Ni,
                                                  const float* __restrict__ bias_a,
                                                  const float* __restrict__ bias_W,
                                                  float* __restrict__ H){
    __shared__ unsigned short buf[4][64][72];
    __shared__ float cspart[8][64];
    __shared__ float csl[64];
    __shared__ float rspart[64][8];
    __shared__ float rsl[64];
    __shared__ float bl[512];
    int t = threadIdx.x;
    int b = blockIdx.x, it = blockIdx.y;       // batch on x: 8 i-tile blocks of a batch share an XCD
    int i0 = it * 64;
    int Nb = (Ni[1] == 0) ? Ni[2*b] : Ni[b];   // int64 vs int32 layout
    int lane = t & 63, w = t >> 6, l15 = lane & 15, quad = lane >> 4;
    int wr = w & 3, wc = w >> 2;
    int r8 = t >> 3, c4 = (t & 7) * 4, c8 = (t & 7) * 8;
    const float* Ab = A + (b*NN + i0)*NN;
    const unsigned short* XWtb = XWt + b*64*NN;
    const unsigned short* XWhb = XWh + b*NN*FD;

    {   // colsum partials from a (tiny, L2-hot; reduced at M-write time)
        int cd = t & 63, cp = t >> 6;
        float s = 0.f;
        #pragma unroll
        for (int i = 0; i < 8; i++) s += a[(cp*8 + i)*64 + cd];
        cspart[cp][cd] = s;
    }
    bl[t] = bias_a[t];

    // ---- phase A: M = A_ @ XWt over 8 k-chunks; A depth-2, XWt depth-1 prefetch ----
    float4 pA[2][2]; uint4 pB;
    pA[0][0] = *(const float4*)&Ab[r8*NN + c4];
    pA[0][1] = *(const float4*)&Ab[r8*NN + 32 + c4];
    pA[1][0] = *(const float4*)&Ab[r8*NN + 64 + c4];
    pA[1][1] = *(const float4*)&Ab[r8*NN + 64 + 32 + c4];
    pB = *(const uint4*)&XWtb[r8*NN + c8];
    f32x4 acc[2] = {{0,0,0,0},{0,0,0,0}};
    float rs = 0.f;
    #pragma unroll
    for (int c = 0; c < 8; c++){
        {   // stage chunk c
            float4 v = pA[c & 1][0];
            rs += v.x + v.y + v.z + v.w;
            ushort4 h; h.x=f2bf(v.x); h.y=f2bf(v.y); h.z=f2bf(v.z); h.w=f2bf(v.w);
            *(ushort4*)&buf[c & 1][r8][c4] = h;
            v = pA[c & 1][1];
            rs += v.x + v.y + v.z + v.w;
            ushort4 h2; h2.x=f2bf(v.x); h2.y=f2bf(v.y); h2.z=f2bf(v.z); h2.w=f2bf(v.w);
            *(ushort4*)&buf[c & 1][r8][32 + c4] = h2;
        }
        *(uint4*)&buf[2 + (c & 1)][r8][c8] = pB;
        if (c < 7) pB = *(const uint4*)&XWtb[r8*NN + (c+1)*64 + c8];  // L2-hot
        __syncthreads();
        if (c < 6){   // depth-2 A prefetch, after barrier (vmcnt drain avoided)
            pA[c & 1][0] = *(const float4*)&Ab[r8*NN + (c+2)*64 + c4];
            pA[c & 1][1] = *(const float4*)&Ab[r8*NN + (c+2)*64 + 32 + c4];
        }
        #pragma unroll
        for (int ks = 0; ks < 2; ks++){
            bf16x8 af = *(const bf16x8*)&buf[c & 1][wr*16 + l15][ks*32 + quad*8];
            #pragma unroll
            for (int nt = 0; nt < 2; nt++){
                bf16x8 bfr = *(const bf16x8*)&buf[2 + (c & 1)][wc*32 + nt*16 + l15][ks*32 + quad*8];
                acc[nt] = __builtin_amdgcn_mfma_f32_16x16x32_bf16(af, bfr, acc[nt], 0, 0, 0);
            }
        }
        if (c == it){   // diagonal of A_: adds XW[i,:] for i < Nb (k==i in this chunk)
            #pragma unroll
            for (int nt = 0; nt < 2; nt++)
                #pragma unroll
                for (int rg = 0; rg < 4; rg++){
                    int iloc = wr*16 + quad*4 + rg;
                    if (i0 + iloc < Nb)
                        acc[nt][rg] += bf2f(buf[2 + (c & 1)][wc*32 + nt*16 + l15][iloc]);
                }
        }
    }
    rspart[r8][t & 7] = rs;
    __syncthreads();
    if (t < 64){
        float s = 0.f;
        #pragma unroll
        for (int p = 0; p < 8; p++) s += cspart[p][t];
        csl[t] = s;
    } else if (t < 128){
        int row = t - 64;
        float s = 0.f;
        #pragma unroll
        for (int p = 0; p < 8; p++) s += rspart[row][p];
        if (i0 + row < Nb) s += 1.f;
        rsl[row] = s;
    }
    __syncthreads();
    // M = acc * colsum[col] -> buf[2] (row-major, A-operand readable)
    #pragma unroll
    for (int nt = 0; nt < 2; nt++){
        float cs = csl[wc*32 + nt*16 + l15];
        #pragma unroll
        for (int rg = 0; rg < 4; rg++)
            buf[2][wr*16 + quad*4 + rg][wc*32 + nt*16 + l15] = f2bf(acc[nt][rg] * cs);
    }
    __syncthreads();
    bf16x8 maf[2];   // hoist M A-frags; buf[2] then free for P
    maf[0] = *(const bf16x8*)&buf[2][wr*16 + l15][quad*8];
    maf[1] = *(const bf16x8*)&buf[2][wr*16 + l15][32 + quad*8];
    float rs_r[4];
    #pragma unroll
    for (int rg = 0; rg < 4; rg++) rs_r[rg] = rsl[wr*16 + quad*4 + rg];

    // ---- phase B: flash over 8 j-chunks; XWh single (buf0), XWt dbuf (buf1/buf3), P=buf2 ----
    {   // pre-stage chunk 0
        uint4 q1 = *(const uint4*)&XWhb[r8*FD + c8];
        uint4 q2 = *(const uint4*)&XWtb[r8*NN + c8];
        *(uint4*)&buf[0][r8][c8] = q1;
        *(uint4*)&buf[1][r8][c8] = q2;
    }
    uint4 q1 = *(const uint4*)&XWhb[(64 + r8)*FD + c8];
    uint4 q2 = *(const uint4*)&XWtb[r8*NN + 64 + c8];
    f32x4 hacc[2] = {{0,0,0,0},{0,0,0,0}};
    #pragma unroll
    for (int jt = 0; jt < 8; jt++){
        __syncthreads();   // B-top: stage(jt) ready; P-WAR; XWt-dbuf WAR
        #pragma unroll
        for (int nt = 0; nt < 2; nt++){
            float bv = bl[jt*64 + wc*32 + nt*16 + l15];
            f32x4 arg = { rs_r[0]*bv, rs_r[1]*bv, rs_r[2]*bv, rs_r[3]*bv };
            #pragma unroll
            for (int ks = 0; ks < 2; ks++){
                bf16x8 bfr = *(const bf16x8*)&buf[0][wc*32 + nt*16 + l15][ks*32 + quad*8];
                arg = __builtin_amdgcn_mfma_f32_16x16x32_bf16(maf[ks], bfr, arg, 0, 0, 0);
            }
            #pragma unroll
            for (int rg = 0; rg < 4; rg++)
                buf[2][wr*16 + quad*4 + rg][wc*32 + nt*16 + l15] = f2bf(fast_tanh(arg[rg]));
        }
        __syncthreads();   // B2: P ready
        {
            const unsigned short (*bT)[72] = buf[(jt & 1) ? 3 : 1];
            #pragma unroll
            for (int ks = 0; ks < 2; ks++){
                bf16x8 paf = *(const bf16x8*)&buf[2][wr*16 + l15][ks*32 + quad*8];
                #pragma unroll
                for (int dt = 0; dt < 2; dt++){
                    bf16x8 bfr = *(const bf16x8*)&bT[wc*32 + dt*16 + l15][ks*32 + quad*8];
                    hacc[dt] = __builtin_amdgcn_mfma_f32_16x16x32_bf16(paf, bfr, hacc[dt], 0, 0, 0);
                }
            }
        }
        if (jt < 7){   // stage jt+1 (XWh->buf0 safe: GEMM1(jt) reads retired at B2)
            *(uint4*)&buf[0][r8][c8] = q1;
            *(uint4*)&buf[(jt & 1) ? 1 : 3][r8][c8] = q2;
            if (jt < 6){
                q1 = *(const uint4*)&XWhb[((jt+2)*64 + r8)*FD + c8];
                q2 = *(const uint4*)&XWtb[r8*NN + (jt+2)*64 + c8];
            }
        }
    }
    #pragma unroll
    for (int dt = 0; dt < 2; dt++){
        float bw = bias_W[wc*32 + dt*16 + l15];
        #pragma unroll
        for (int rg = 0; rg < 4; rg++)
            H[(b*NN + i0 + wr*16 + quad*4 + rg)*FD + wc*32 + dt*16 + l15] = hacc[dt][rg] + bw;
    }
}

extern "C" void kernel_launch(void* const* d_in, const int* in_sizes, int n_in,
                              void* d_out, int out_size, void* d_ws, size_t ws_size,
                              hipStream_t stream){
    const float* X      = (const float*)d_in[0];
    const float* A      = (const float*)d_in[1];
    const int*   N      = (const int*)  d_in[2];
    const float* W      = (const float*)d_in[3];
    const float* a      = (const float*)d_in[4];
    const float* bias_W = (const float*)d_in[5];
    const float* bias_a = (const float*)d_in[6];
    float* H = (float*)d_out;
    char* ws = (char*)d_ws;

    unsigned short* XWh = (unsigned short*)(ws);              // 4 MB
    unsigned short* XWt = (unsigned short*)(ws + (4u<<20));   // 4 MB

    k_xw   <<<BB * NN / 64, 256, 0, stream>>>(X, W, XWh, XWt);
    k_fused<<<dim3(BB, 8), 512, 0, stream>>>(A, XWh, XWt, a, N, bias_a, bias_W, H);
}